// Round 5
// baseline (450.087 us; speedup 1.0000x reference)
//
#include <hip/hip_runtime.h>
#include <math.h>
#include <float.h>

#define NROWS 16384
#define KCODES 8192
#define DIM 256

// ws layout (4B units)
#define WS_CIDX 0                                  // 16384*8 int4 (2 MB)
#define WS_ZZ   (NROWS * 8 * 4)
#define WS_EE   (WS_ZZ + NROWS)
#define WS_LOSS (WS_EE + KCODES)
#define WS_ZB   (WS_LOSS + 64)                     // z bf16: 16384*256*2B = 2097152 u32
#define WS_EB   (WS_ZB + NROWS * DIM / 2)          // emb bf16: 1048576 u32
// total ~3.7M u32 = 14.8 MB

typedef __attribute__((ext_vector_type(8))) short bf16x8;
typedef __attribute__((ext_vector_type(4))) float f32x4;

__device__ __forceinline__ unsigned cvt2(float lo, float hi) {
  unsigned r;
  asm("v_cvt_pk_bf16_f32 %0, %1, %2" : "=v"(r) : "v"(lo), "v"(hi));
  return r;
}
__device__ __forceinline__ void gl_lds16(const void* gsrc, void* lds) {
  __builtin_amdgcn_global_load_lds(
      (const __attribute__((address_space(1))) unsigned int*)gsrc,
      (__attribute__((address_space(3))) unsigned int*)lds, 16, 0, 0);
}
__device__ __forceinline__ unsigned umn(unsigned a, unsigned b) { return a < b ? a : b; }
__device__ __forceinline__ unsigned umx(unsigned a, unsigned b) { return a > b ? a : b; }
__device__ __forceinline__ void ce32(unsigned& a, unsigned& b) {
  unsigned lo = umn(a, b); b = umx(a, b); a = lo;
}
__device__ __forceinline__ void mrg4(unsigned m[4], const unsigned o[4]) {
  m[0] = umn(m[0], o[3]); m[1] = umn(m[1], o[2]);
  m[2] = umn(m[2], o[1]); m[3] = umn(m[3], o[0]);
  ce32(m[0], m[2]); ce32(m[1], m[3]); ce32(m[0], m[1]); ce32(m[2], m[3]);
}
__device__ __forceinline__ void sort4(unsigned& a, unsigned& b, unsigned& c, unsigned& d) {
  ce32(a, b); ce32(c, d); ce32(a, c); ce32(b, d); ce32(b, c);
}

// ---- exact numpy scalar-pairwise sum of squares over 256 contiguous f32 ----
__device__ __forceinline__ float np_sumsq256(const float* __restrict__ p) {
#pragma clang fp contract(off)
  float s0 = 0.f, s1 = 0.f;
  for (int h = 0; h < 2; ++h) {
    const float* x = p + h * 128;
    float r0, r1, r2, r3, r4, r5, r6, r7;
    {
      float4 a = *reinterpret_cast<const float4*>(x);
      float4 b = *reinterpret_cast<const float4*>(x + 4);
      r0 = a.x * a.x; r1 = a.y * a.y; r2 = a.z * a.z; r3 = a.w * a.w;
      r4 = b.x * b.x; r5 = b.y * b.y; r6 = b.z * b.z; r7 = b.w * b.w;
    }
    for (int g = 1; g < 16; ++g) {
      float4 a = *reinterpret_cast<const float4*>(x + g * 8);
      float4 b = *reinterpret_cast<const float4*>(x + g * 8 + 4);
      float p0 = a.x * a.x, p1 = a.y * a.y, p2 = a.z * a.z, p3 = a.w * a.w;
      float p4 = b.x * b.x, p5 = b.y * b.y, p6 = b.z * b.z, p7 = b.w * b.w;
      r0 += p0; r1 += p1; r2 += p2; r3 += p3;
      r4 += p4; r5 += p5; r6 += p6; r7 += p7;
    }
    float t = ((r0 + r1) + (r2 + r3)) + ((r4 + r5) + (r6 + r7));
    if (h == 0) s0 = t; else s1 = t;
  }
  return s0 + s1;
}

__global__ __launch_bounds__(256) void vq_prep_zz(const float* __restrict__ z,
                                                  float* __restrict__ zz,
                                                  float* __restrict__ lossAcc) {
  const int row = blockIdx.x * 256 + threadIdx.x;
  if (row == 0) *lossAcc = 0.0f;
  zz[row] = np_sumsq256(z + row * DIM);
}

__global__ __launch_bounds__(256) void vq_prep_ee(const float* __restrict__ emb,
                                                  float* __restrict__ ee) {
  const int c = blockIdx.x * 256 + threadIdx.x;
  ee[c] = np_sumsq256(emb + c * DIM);
}

// ---- f32 -> bf16 conversion of z and emb (coalesced, 8 elems/thread) ----
#define CVT_ZBLK (NROWS * DIM / 8 / 256)    // 2048
#define CVT_EBLK (KCODES * DIM / 8 / 256)   // 1024
__global__ __launch_bounds__(256) void vq_cvt(const float* __restrict__ z,
                                              const float* __restrict__ emb,
                                              uint4* __restrict__ zb,
                                              uint4* __restrict__ eb) {
  const int bid = blockIdx.x;
  const float* s;
  uint4* d;
  int i;
  if (bid < CVT_ZBLK) { s = z; d = zb; i = bid * 256 + threadIdx.x; }
  else { s = emb; d = eb; i = (bid - CVT_ZBLK) * 256 + threadIdx.x; }
  const float4 a = *reinterpret_cast<const float4*>(s + i * 8);
  const float4 b = *reinterpret_cast<const float4*>(s + i * 8 + 4);
  d[i] = make_uint4(cvt2(a.x, a.y), cvt2(a.z, a.w), cvt2(b.x, b.y), cvt2(b.z, b.w));
}

// ---------------- stage A: bf16 MFMA ranking + packed-key top-4 per 1024-code range ----------------
// grid: (NROWS/128, 8). Block: 4 waves (wr row-half, wc code-half). Wave tile 64 rows x 128 codes.
// Staging via global_load_lds(16B) from pre-converted bf16, source pre-swizzled, LDS linear.
__global__ __launch_bounds__(256, 3) void vq_stageA(const unsigned* __restrict__ zb,
                                                    const unsigned* __restrict__ eb,
                                                    int4* __restrict__ candIdx) {
  __shared__ short es[256 * 64];                 // [code][k] swizzled, 32 KB (merge buf aliased)
  __shared__ short zs[128 * 64];                 // [row][k] swizzled, 16 KB

  const int tid = threadIdx.x;
  const int wave = tid >> 6, lane = tid & 63;
  const int wr = wave >> 1, wc = wave & 1;
  const int g = lane >> 4, r16 = lane & 15;
  const int rowBase = blockIdx.x * 128;
  const int crange = blockIdx.y;
  const int swz = (r16 & 7) << 4;

  // per-lane pre-swizzled staging source addresses (bytes); global row = 512 B
  const int l8 = lane >> 3, l7 = lane & 7;
  const int swzoff = ((l7 ^ l8) << 4);
  const char* ebB = reinterpret_cast<const char*>(eb);
  const char* zbB = reinterpret_cast<const char*>(zb);
  const char* zsrc = zbB + (size_t)(rowBase + wave * 32 + l8) * 512 + swzoff;
  char* esDst = reinterpret_cast<char*>(es) + wave * 8 * 1024;
  char* zsDst = reinterpret_cast<char*>(zs) + wave * 4 * 1024;

  unsigned run[4][4];
  #pragma unroll
  for (int bj = 0; bj < 4; ++bj)
    #pragma unroll
    for (int q = 0; q < 4; ++q) run[bj][q] = 0xFFFFFFFFu;

  for (int cc = 0; cc < 4; ++cc) {
    const char* esrc = ebB + (size_t)(crange * 1024 + cc * 256 + wave * 64 + l8) * 512 + swzoff;
    f32x4 acc[8][4];
    #pragma unroll
    for (int ai = 0; ai < 8; ++ai)
      #pragma unroll
      for (int bj = 0; bj < 4; ++bj) acc[ai][bj] = (f32x4){0.f, 0.f, 0.f, 0.f};

    for (int kc = 0; kc < 4; ++kc) {
      // stage: 8 x 1KB (codes) + 4 x 1KB (rows) per wave, async to LDS
      #pragma unroll
      for (int i = 0; i < 8; ++i)
        gl_lds16(esrc + i * 4096 + kc * 128, esDst + i * 1024);
      #pragma unroll
      for (int i = 0; i < 4; ++i)
        gl_lds16(zsrc + i * 4096 + kc * 128, zsDst + i * 1024);
      __syncthreads();                 // drains vmcnt: tiles resident

      #pragma unroll
      for (int ks2 = 0; ks2 < 2; ++ks2) {
        const int kb = ks2 * 64 + g * 16;
        bf16x8 A[8], B[4];
        #pragma unroll
        for (int ai = 0; ai < 8; ++ai) {
          const int cl = wc * 128 + ai * 16 + r16;
          A[ai] = *reinterpret_cast<const bf16x8*>(
              reinterpret_cast<const char*>(es) + ((cl * 128 + kb) ^ swz));
        }
        #pragma unroll
        for (int bj = 0; bj < 4; ++bj) {
          const int rl = wr * 64 + bj * 16 + r16;
          B[bj] = *reinterpret_cast<const bf16x8*>(
              reinterpret_cast<const char*>(zs) + ((rl * 128 + kb) ^ swz));
        }
        #pragma unroll
        for (int ai = 0; ai < 8; ++ai)
          #pragma unroll
          for (int bj = 0; bj < 4; ++bj)
            acc[ai][bj] = __builtin_amdgcn_mfma_f32_16x16x32_bf16(A[ai], B[bj], acc[ai][bj], 0, 0, 0);
      }
      __syncthreads();                 // readers done before next overwrite
    }

    // selection: packed keys, top-4 per (row, cc-subtile) merged into running top-4
    #pragma unroll
    for (int bj = 0; bj < 4; ++bj) {
      unsigned q4[8][4];
      #pragma unroll
      for (int ai = 0; ai < 8; ++ai) {
        const unsigned base9 = (cc << 7) | (ai << 4) | (g << 2);
        unsigned k0 = (__float_as_uint(1.5f - acc[ai][bj][0]) << 9) | base9;
        unsigned k1 = (__float_as_uint(1.5f - acc[ai][bj][1]) << 9) | (base9 + 1);
        unsigned k2 = (__float_as_uint(1.5f - acc[ai][bj][2]) << 9) | (base9 + 2);
        unsigned k3 = (__float_as_uint(1.5f - acc[ai][bj][3]) << 9) | (base9 + 3);
        sort4(k0, k1, k2, k3);
        q4[ai][0] = k0; q4[ai][1] = k1; q4[ai][2] = k2; q4[ai][3] = k3;
      }
      mrg4(q4[0], q4[1]); mrg4(q4[2], q4[3]); mrg4(q4[4], q4[5]); mrg4(q4[6], q4[7]);
      mrg4(q4[0], q4[2]); mrg4(q4[4], q4[6]);
      mrg4(q4[0], q4[4]);
      mrg4(run[bj], q4[0]);
    }
  }

  // butterfly across the 4 k-lane groups
  #pragma unroll
  for (int bj = 0; bj < 4; ++bj) {
    #pragma unroll
    for (int m = 16; m < 64; m <<= 1) {
      unsigned o[4];
      #pragma unroll
      for (int q = 0; q < 4; ++q) o[q] = __shfl_xor(run[bj][q], m, 64);
      mrg4(run[bj], o);
    }
  }
  // cross-wave merge via LDS (aliased onto es; all es reads completed)
  unsigned long long (*mrgp)[2][4] = reinterpret_cast<unsigned long long(*)[2][4]>(es);
  if (lane < 16) {
    #pragma unroll
    for (int bj = 0; bj < 4; ++bj) {
      const int rl = wr * 64 + bj * 16 + r16;
      #pragma unroll
      for (int q = 0; q < 4; ++q) {
        const unsigned k = run[bj][q];
        const unsigned cid = k & 511u;
        const unsigned cir = ((cid >> 7) << 8) | (wc << 7) | (cid & 127u);
        mrgp[rl][wc][q] = (((unsigned long long)(k >> 9)) << 10) | cir;
      }
    }
  }
  __syncthreads();
  if (tid < 128) {
    unsigned long long a0 = mrgp[tid][0][0], a1 = mrgp[tid][0][1], a2 = mrgp[tid][0][2], a3 = mrgp[tid][0][3];
    unsigned long long b0 = mrgp[tid][1][0], b1 = mrgp[tid][1][1], b2 = mrgp[tid][1][2], b3 = mrgp[tid][1][3];
    a0 = a0 < b3 ? a0 : b3; a1 = a1 < b2 ? a1 : b2;
    a2 = a2 < b1 ? a2 : b1; a3 = a3 < b0 ? a3 : b0;
    unsigned long long t;
    if (a2 < a0) { t = a0; a0 = a2; a2 = t; }
    if (a3 < a1) { t = a1; a1 = a3; a3 = t; }
    if (a1 < a0) { t = a0; a0 = a1; a1 = t; }
    if (a3 < a2) { t = a2; a2 = a3; a3 = t; }
    const int base = crange * 1024;
    candIdx[(rowBase + tid) * 8 + crange] =
        make_int4(base + (int)(a0 & 1023u), base + (int)(a1 & 1023u),
                  base + (int)(a2 & 1023u), base + (int)(a3 & 1023u));
  }
}

// ---------------- stage B: literal np-f32 re-score (sequential fmaf chain) + lexmin ----------------
__global__ __launch_bounds__(256) void vq_stageB(const float* __restrict__ z,
                                                 const float* __restrict__ emb,
                                                 const float* __restrict__ zz,
                                                 const float* __restrict__ ee,
                                                 const int4* __restrict__ candIdx,
                                                 float* __restrict__ outq,
                                                 float* __restrict__ outi,
                                                 float* __restrict__ lossAcc) {
#pragma clang fp contract(off)
  __shared__ float lred[8];
  const int tid = threadIdx.x;
  const int grp = tid >> 5;              // 8 rows per block
  const int slot = tid & 31;             // 32 candidates per row
  const int row = blockIdx.x * 8 + grp;

  const int4 c4 = candIdx[row * 8 + (slot >> 2)];
  const int sel = slot & 3;
  const int ci = sel == 0 ? c4.x : sel == 1 ? c4.y : sel == 2 ? c4.z : c4.w;

  const float* zr = z + row * DIM;
  const float* er = emb + ci * DIM;
  float acc = 0.0f;
  #pragma unroll 4
  for (int k = 0; k < DIM; k += 4) {
    const float4 a = *reinterpret_cast<const float4*>(zr + k);
    const float4 b = *reinterpret_cast<const float4*>(er + k);
    acc = fmaf(a.x, b.x, acc);
    acc = fmaf(a.y, b.y, acc);
    acc = fmaf(a.z, b.z, acc);
    acc = fmaf(a.w, b.w, acc);
  }
  const float t = zz[row] + ee[ci];
  const float m2 = 2.0f * acc;
  const float s = t - m2;

  unsigned long long pk =
      (((unsigned long long)__float_as_uint(s)) << 32) | (unsigned int)ci;
  #pragma unroll
  for (int mm_ = 1; mm_ < 32; mm_ <<= 1) {
    const unsigned long long o = __shfl_xor(pk, mm_, 64);
    pk = (o < pk) ? o : pk;
  }
  const int bi = (int)(pk & 0xffffffffu);

  const float4* eb4 = reinterpret_cast<const float4*>(emb + bi * DIM);
  const float4* zb4 = reinterpret_cast<const float4*>(zr);
  float l = 0.0f;
  #pragma unroll
  for (int q = 0; q < 2; ++q) {
    const float4 e4 = eb4[slot * 2 + q];
    const float4 z4 = zb4[slot * 2 + q];
    float4 o4;
    const float dx = e4.x - z4.x, dy = e4.y - z4.y, dz = e4.z - z4.z, dw = e4.w - z4.w;
    o4.x = z4.x + dx; o4.y = z4.y + dy; o4.z = z4.z + dz; o4.w = z4.w + dw;
    *reinterpret_cast<float4*>(outq + row * DIM + slot * 8 + q * 4) = o4;
    l += dx * dx; l += dy * dy; l += dz * dz; l += dw * dw;
  }
  if (slot == 0) outi[row] = (float)bi;

  #pragma unroll
  for (int mm_ = 1; mm_ < 32; mm_ <<= 1) l += __shfl_xor(l, mm_, 64);
  if (slot == 0) lred[grp] = l;
  __syncthreads();
  if (tid == 0) {
    float tt = 0.f;
    #pragma unroll
    for (int g = 0; g < 8; ++g) tt += lred[g];
    atomicAdd(lossAcc, tt);
  }
}

__global__ void vq_fin(const float* __restrict__ lossAcc, float* __restrict__ outLoss) {
  *outLoss = 1.25f * (*lossAcc) * (1.0f / 4194304.0f);
}

extern "C" void kernel_launch(void* const* d_in, const int* in_sizes, int n_in,
                              void* d_out, int out_size, void* d_ws, size_t ws_size,
                              hipStream_t stream) {
  const float* z = (const float*)d_in[0];
  const float* emb = (const float*)d_in[1];
  float* out = (float*)d_out;
  float* wsf = (float*)d_ws;
  int4* candIdx = (int4*)(wsf + WS_CIDX);
  float* zz = wsf + WS_ZZ;
  float* ee = wsf + WS_EE;
  float* lossAcc = wsf + WS_LOSS;
  uint4* zb = (uint4*)(wsf + WS_ZB);
  uint4* eb = (uint4*)(wsf + WS_EB);

  vq_prep_zz<<<NROWS / 256, 256, 0, stream>>>(z, zz, lossAcc);
  vq_prep_ee<<<KCODES / 256, 256, 0, stream>>>(emb, ee);
  vq_cvt<<<CVT_ZBLK + CVT_EBLK, 256, 0, stream>>>(z, emb, zb, eb);
  vq_stageA<<<dim3(NROWS / 128, 8), 256, 0, stream>>>((const unsigned*)zb, (const unsigned*)eb, candIdx);
  vq_stageB<<<NROWS / 8, 256, 0, stream>>>(z, emb, zz, ee, candIdx,
                                           out, out + NROWS * DIM, lossAcc);
  vq_fin<<<1, 1, 0, stream>>>(lossAcc, out + NROWS * DIM + NROWS);
}

// Round 6
// 266.733 us; speedup vs baseline: 1.6874x; 1.6874x over previous
//
#include <hip/hip_runtime.h>
#include <math.h>
#include <float.h>

#define NROWS 16384
#define KCODES 8192
#define DIM 256

// ws layout (4B units)
#define WS_CIDX 0                                  // 16384*8 int4 (2 MB)
#define WS_ZZ   (NROWS * 8 * 4)
#define WS_EE   (WS_ZZ + NROWS)
#define WS_LOSS (WS_EE + KCODES)
#define WS_ZB   (WS_LOSS + 64)                     // z bf16
#define WS_EB   (WS_ZB + NROWS * DIM / 2)          // emb bf16

typedef __attribute__((ext_vector_type(8))) short bf16x8;
typedef __attribute__((ext_vector_type(4))) float f32x4;

__device__ __forceinline__ unsigned cvt2(float lo, float hi) {
  unsigned r;
  asm("v_cvt_pk_bf16_f32 %0, %1, %2" : "=v"(r) : "v"(lo), "v"(hi));
  return r;
}
__device__ __forceinline__ void gl_lds16(const void* gsrc, void* lds) {
  __builtin_amdgcn_global_load_lds(
      (const __attribute__((address_space(1))) unsigned int*)gsrc,
      (__attribute__((address_space(3))) unsigned int*)lds, 16, 0, 0);
}
__device__ __forceinline__ unsigned umn(unsigned a, unsigned b) { return a < b ? a : b; }
__device__ __forceinline__ unsigned umx(unsigned a, unsigned b) { return a > b ? a : b; }
__device__ __forceinline__ void ce32(unsigned& a, unsigned& b) {
  unsigned lo = umn(a, b); b = umx(a, b); a = lo;
}
__device__ __forceinline__ void mrg4(unsigned m[4], const unsigned o[4]) {
  m[0] = umn(m[0], o[3]); m[1] = umn(m[1], o[2]);
  m[2] = umn(m[2], o[1]); m[3] = umn(m[3], o[0]);
  ce32(m[0], m[2]); ce32(m[1], m[3]); ce32(m[0], m[1]); ce32(m[2], m[3]);
}
__device__ __forceinline__ void sort4(unsigned& a, unsigned& b, unsigned& c, unsigned& d) {
  ce32(a, b); ce32(c, d); ce32(a, c); ce32(b, d); ce32(b, c);
}

// ---- exact numpy scalar-pairwise sum of squares over 256 contiguous f32 ----
__device__ __forceinline__ float np_sumsq256(const float* __restrict__ p) {
#pragma clang fp contract(off)
  float s0 = 0.f, s1 = 0.f;
  for (int h = 0; h < 2; ++h) {
    const float* x = p + h * 128;
    float r0, r1, r2, r3, r4, r5, r6, r7;
    {
      float4 a = *reinterpret_cast<const float4*>(x);
      float4 b = *reinterpret_cast<const float4*>(x + 4);
      r0 = a.x * a.x; r1 = a.y * a.y; r2 = a.z * a.z; r3 = a.w * a.w;
      r4 = b.x * b.x; r5 = b.y * b.y; r6 = b.z * b.z; r7 = b.w * b.w;
    }
    for (int g = 1; g < 16; ++g) {
      float4 a = *reinterpret_cast<const float4*>(x + g * 8);
      float4 b = *reinterpret_cast<const float4*>(x + g * 8 + 4);
      float p0 = a.x * a.x, p1 = a.y * a.y, p2 = a.z * a.z, p3 = a.w * a.w;
      float p4 = b.x * b.x, p5 = b.y * b.y, p6 = b.z * b.z, p7 = b.w * b.w;
      r0 += p0; r1 += p1; r2 += p2; r3 += p3;
      r4 += p4; r5 += p5; r6 += p6; r7 += p7;
    }
    float t = ((r0 + r1) + (r2 + r3)) + ((r4 + r5) + (r6 + r7));
    if (h == 0) s0 = t; else s1 = t;
  }
  return s0 + s1;
}

__global__ __launch_bounds__(256) void vq_prep_zz(const float* __restrict__ z,
                                                  float* __restrict__ zz,
                                                  float* __restrict__ lossAcc) {
  const int row = blockIdx.x * 256 + threadIdx.x;
  if (row == 0) *lossAcc = 0.0f;
  zz[row] = np_sumsq256(z + row * DIM);
}

__global__ __launch_bounds__(256) void vq_prep_ee(const float* __restrict__ emb,
                                                  float* __restrict__ ee) {
  const int c = blockIdx.x * 256 + threadIdx.x;
  ee[c] = np_sumsq256(emb + c * DIM);
}

// ---- f32 -> bf16 conversion of z and emb ----
#define CVT_ZBLK (NROWS * DIM / 8 / 256)    // 2048
#define CVT_EBLK (KCODES * DIM / 8 / 256)   // 1024
__global__ __launch_bounds__(256) void vq_cvt(const float* __restrict__ z,
                                              const float* __restrict__ emb,
                                              uint4* __restrict__ zb,
                                              uint4* __restrict__ eb) {
  const int bid = blockIdx.x;
  const float* s;
  uint4* d;
  int i;
  if (bid < CVT_ZBLK) { s = z; d = zb; i = bid * 256 + threadIdx.x; }
  else { s = emb; d = eb; i = (bid - CVT_ZBLK) * 256 + threadIdx.x; }
  const float4 a = *reinterpret_cast<const float4*>(s + i * 8);
  const float4 b = *reinterpret_cast<const float4*>(s + i * 8 + 4);
  d[i] = make_uint4(cvt2(a.x, a.y), cvt2(a.z, a.w), cvt2(b.x, b.y), cvt2(b.z, b.w));
}

// ---------------- stage A: bf16 MFMA ranking + packed-key top-4 per 1024-code range ----------------
__global__ __launch_bounds__(256, 2) void vq_stageA(const unsigned* __restrict__ zb,
                                                    const unsigned* __restrict__ eb,
                                                    int4* __restrict__ candIdx) {
  __shared__ short es[256 * 64];                 // [code][k] swizzled, 32 KB (merge buf aliased)
  __shared__ short zs[128 * 64];                 // [row][k] swizzled, 16 KB

  const int tid = threadIdx.x;
  const int wave = tid >> 6, lane = tid & 63;
  const int wr = wave >> 1, wc = wave & 1;
  const int g = lane >> 4, r16 = lane & 15;
  const int rowBase = blockIdx.x * 128;
  const int crange = blockIdx.y;
  const int swz = (r16 & 7) << 4;

  const int l8 = lane >> 3, l7 = lane & 7;
  const int swzoff = ((l7 ^ l8) << 4);
  const char* ebB = reinterpret_cast<const char*>(eb);
  const char* zbB = reinterpret_cast<const char*>(zb);
  const char* zsrc = zbB + (size_t)(rowBase + wave * 32 + l8) * 512 + swzoff;
  char* esDst = reinterpret_cast<char*>(es) + wave * 8 * 1024;
  char* zsDst = reinterpret_cast<char*>(zs) + wave * 4 * 1024;

  unsigned run[4][4];
  #pragma unroll
  for (int bj = 0; bj < 4; ++bj)
    #pragma unroll
    for (int q = 0; q < 4; ++q) run[bj][q] = 0xFFFFFFFFu;

  for (int cc = 0; cc < 4; ++cc) {
    const char* esrc = ebB + (size_t)(crange * 1024 + cc * 256 + wave * 64 + l8) * 512 + swzoff;
    f32x4 acc[8][4];
    #pragma unroll
    for (int ai = 0; ai < 8; ++ai)
      #pragma unroll
      for (int bj = 0; bj < 4; ++bj) acc[ai][bj] = (f32x4){0.f, 0.f, 0.f, 0.f};

    for (int kc = 0; kc < 4; ++kc) {
      #pragma unroll
      for (int i = 0; i < 8; ++i)
        gl_lds16(esrc + i * 4096 + kc * 128, esDst + i * 1024);
      #pragma unroll
      for (int i = 0; i < 4; ++i)
        gl_lds16(zsrc + i * 4096 + kc * 128, zsDst + i * 1024);
      __syncthreads();

      #pragma unroll
      for (int ks2 = 0; ks2 < 2; ++ks2) {
        const int kb = ks2 * 64 + g * 16;
        bf16x8 A[8], B[4];
        #pragma unroll
        for (int ai = 0; ai < 8; ++ai) {
          const int cl = wc * 128 + ai * 16 + r16;
          A[ai] = *reinterpret_cast<const bf16x8*>(
              reinterpret_cast<const char*>(es) + ((cl * 128 + kb) ^ swz));
        }
        #pragma unroll
        for (int bj = 0; bj < 4; ++bj) {
          const int rl = wr * 64 + bj * 16 + r16;
          B[bj] = *reinterpret_cast<const bf16x8*>(
              reinterpret_cast<const char*>(zs) + ((rl * 128 + kb) ^ swz));
        }
        #pragma unroll
        for (int ai = 0; ai < 8; ++ai)
          #pragma unroll
          for (int bj = 0; bj < 4; ++bj)
            acc[ai][bj] = __builtin_amdgcn_mfma_f32_16x16x32_bf16(A[ai], B[bj], acc[ai][bj], 0, 0, 0);
      }
      __syncthreads();
    }

    #pragma unroll
    for (int bj = 0; bj < 4; ++bj) {
      unsigned q4[8][4];
      #pragma unroll
      for (int ai = 0; ai < 8; ++ai) {
        const unsigned base9 = (cc << 7) | (ai << 4) | (g << 2);
        unsigned k0 = (__float_as_uint(1.5f - acc[ai][bj][0]) << 9) | base9;
        unsigned k1 = (__float_as_uint(1.5f - acc[ai][bj][1]) << 9) | (base9 + 1);
        unsigned k2 = (__float_as_uint(1.5f - acc[ai][bj][2]) << 9) | (base9 + 2);
        unsigned k3 = (__float_as_uint(1.5f - acc[ai][bj][3]) << 9) | (base9 + 3);
        sort4(k0, k1, k2, k3);
        q4[ai][0] = k0; q4[ai][1] = k1; q4[ai][2] = k2; q4[ai][3] = k3;
      }
      mrg4(q4[0], q4[1]); mrg4(q4[2], q4[3]); mrg4(q4[4], q4[5]); mrg4(q4[6], q4[7]);
      mrg4(q4[0], q4[2]); mrg4(q4[4], q4[6]);
      mrg4(q4[0], q4[4]);
      mrg4(run[bj], q4[0]);
    }
  }

  #pragma unroll
  for (int bj = 0; bj < 4; ++bj) {
    #pragma unroll
    for (int m = 16; m < 64; m <<= 1) {
      unsigned o[4];
      #pragma unroll
      for (int q = 0; q < 4; ++q) o[q] = __shfl_xor(run[bj][q], m, 64);
      mrg4(run[bj], o);
    }
  }
  unsigned long long (*mrgp)[2][4] = reinterpret_cast<unsigned long long(*)[2][4]>(es);
  if (lane < 16) {
    #pragma unroll
    for (int bj = 0; bj < 4; ++bj) {
      const int rl = wr * 64 + bj * 16 + r16;
      #pragma unroll
      for (int q = 0; q < 4; ++q) {
        const unsigned k = run[bj][q];
        const unsigned cid = k & 511u;
        const unsigned cir = ((cid >> 7) << 8) | (wc << 7) | (cid & 127u);
        mrgp[rl][wc][q] = (((unsigned long long)(k >> 9)) << 10) | cir;
      }
    }
  }
  __syncthreads();
  if (tid < 128) {
    unsigned long long a0 = mrgp[tid][0][0], a1 = mrgp[tid][0][1], a2 = mrgp[tid][0][2], a3 = mrgp[tid][0][3];
    unsigned long long b0 = mrgp[tid][1][0], b1 = mrgp[tid][1][1], b2 = mrgp[tid][1][2], b3 = mrgp[tid][1][3];
    a0 = a0 < b3 ? a0 : b3; a1 = a1 < b2 ? a1 : b2;
    a2 = a2 < b1 ? a2 : b1; a3 = a3 < b0 ? a3 : b0;
    unsigned long long t;
    if (a2 < a0) { t = a0; a0 = a2; a2 = t; }
    if (a3 < a1) { t = a1; a1 = a3; a3 = t; }
    if (a1 < a0) { t = a0; a0 = a1; a1 = t; }
    if (a3 < a2) { t = a2; a2 = a3; a3 = t; }
    const int base = crange * 1024;
    candIdx[(rowBase + tid) * 8 + crange] =
        make_int4(base + (int)(a0 & 1023u), base + (int)(a1 & 1023u),
                  base + (int)(a2 & 1023u), base + (int)(a3 & 1023u));
  }
}

// ---------------- stage B: LDS-coalesced exact np-f32 re-score + lexmin ----------------
// Block: 8 z-rows x 32 candidates = 256 chains. emb candidate rows staged through LDS in
// 4 k-chunks of 64 floats, coalesced loads, pad-65 rows (store banks distinct, read 2-way).
// Chain arithmetic (sequential fmaf, k ascending) is bit-identical to the R3/R4 passing version.
__global__ __launch_bounds__(256) void vq_stageB(const float* __restrict__ z,
                                                 const float* __restrict__ emb,
                                                 const float* __restrict__ zz,
                                                 const float* __restrict__ ee,
                                                 const int* __restrict__ candFlat,
                                                 float* __restrict__ outq,
                                                 float* __restrict__ outi,
                                                 float* __restrict__ lossAcc) {
#pragma clang fp contract(off)
  __shared__ float els[256 * 65];   // 66.56 KB
  __shared__ float zls[8 * 68];
  __shared__ int clds[256];
  __shared__ float lred[8];

  const int tid = threadIdx.x;
  const int wave = tid >> 6, lane = tid & 63;
  const int grp = tid >> 5;              // z-row within block
  const int slot = tid & 31;             // candidate slot
  const int rowBase = blockIdx.x * 8;
  const int row = rowBase + grp;

  // my candidate (candFlat = candIdx as flat ints: [row][32])
  const int ci = candFlat[row * 32 + slot];
  clds[tid] = ci;
  __syncthreads();

  float acc = 0.0f;
  #pragma unroll 1
  for (int chunk = 0; chunk < 4; ++chunk) {
    // stage z slices: 8 rows x 64 floats
    #pragma unroll
    for (int it = 0; it < 2; ++it) {
      const int f = it * 256 + tid;
      const int zr = f >> 6, zk = f & 63;
      zls[zr * 68 + zk] = z[(rowBase + zr) * DIM + chunk * 64 + zk];
    }
    // stage emb slices: 256 candidate rows x 64 floats, one row-slice per wave-instruction
    #pragma unroll 8
    for (int it = 0; it < 64; ++it) {
      const int slice = it * 4 + wave;
      const int sci = clds[slice];                     // LDS broadcast
      els[slice * 65 + lane] = emb[sci * DIM + chunk * 64 + lane];
    }
    __syncthreads();
    // advance my chain by 64 sequential fmas (exact order: k ascending)
    const float* myE = els + tid * 65;
    const float* myZ = zls + grp * 68;
    #pragma unroll 16
    for (int k = 0; k < 64; ++k)
      acc = fmaf(myZ[k], myE[k], acc);
    __syncthreads();
  }

  // literal np sequence: d = fl(fl(zz + ee) - fl(2*mm))
  const float t = zz[row] + ee[ci];
  const float m2 = 2.0f * acc;
  const float s = t - m2;

  unsigned long long pk =
      (((unsigned long long)__float_as_uint(s)) << 32) | (unsigned int)ci;
  #pragma unroll
  for (int mm_ = 1; mm_ < 32; mm_ <<= 1) {
    const unsigned long long o = __shfl_xor(pk, mm_, 64);
    pk = (o < pk) ? o : pk;
  }
  const int bi = (int)(pk & 0xffffffffu);

  const float4* eb4 = reinterpret_cast<const float4*>(emb + bi * DIM);
  const float4* zb4 = reinterpret_cast<const float4*>(z + row * DIM);
  float l = 0.0f;
  #pragma unroll
  for (int q = 0; q < 2; ++q) {
    const float4 e4 = eb4[slot * 2 + q];
    const float4 z4 = zb4[slot * 2 + q];
    float4 o4;
    const float dx = e4.x - z4.x, dy = e4.y - z4.y, dz = e4.z - z4.z, dw = e4.w - z4.w;
    o4.x = z4.x + dx; o4.y = z4.y + dy; o4.z = z4.z + dz; o4.w = z4.w + dw;
    *reinterpret_cast<float4*>(outq + row * DIM + slot * 8 + q * 4) = o4;
    l += dx * dx; l += dy * dy; l += dz * dz; l += dw * dw;
  }
  if (slot == 0) outi[row] = (float)bi;

  #pragma unroll
  for (int mm_ = 1; mm_ < 32; mm_ <<= 1) l += __shfl_xor(l, mm_, 64);
  if (slot == 0) lred[grp] = l;
  __syncthreads();
  if (tid == 0) {
    float tt = 0.f;
    #pragma unroll
    for (int g2 = 0; g2 < 8; ++g2) tt += lred[g2];
    atomicAdd(lossAcc, tt);
  }
}

__global__ void vq_fin(const float* __restrict__ lossAcc, float* __restrict__ outLoss) {
  *outLoss = 1.25f * (*lossAcc) * (1.0f / 4194304.0f);
}

extern "C" void kernel_launch(void* const* d_in, const int* in_sizes, int n_in,
                              void* d_out, int out_size, void* d_ws, size_t ws_size,
                              hipStream_t stream) {
  const float* z = (const float*)d_in[0];
  const float* emb = (const float*)d_in[1];
  float* out = (float*)d_out;
  float* wsf = (float*)d_ws;
  int4* candIdx = (int4*)(wsf + WS_CIDX);
  float* zz = wsf + WS_ZZ;
  float* ee = wsf + WS_EE;
  float* lossAcc = wsf + WS_LOSS;
  uint4* zb = (uint4*)(wsf + WS_ZB);
  uint4* eb = (uint4*)(wsf + WS_EB);

  vq_prep_zz<<<NROWS / 256, 256, 0, stream>>>(z, zz, lossAcc);
  vq_prep_ee<<<KCODES / 256, 256, 0, stream>>>(emb, ee);
  vq_cvt<<<CVT_ZBLK + CVT_EBLK, 256, 0, stream>>>(z, emb, zb, eb);
  vq_stageA<<<dim3(NROWS / 128, 8), 256, 0, stream>>>((const unsigned*)zb, (const unsigned*)eb, candIdx);
  vq_stageB<<<NROWS / 8, 256, 0, stream>>>(z, emb, zz, ee, (const int*)candIdx,
                                           out, out + NROWS * DIM, lossAcc);
  vq_fin<<<1, 1, 0, stream>>>(lossAcc, out + NROWS * DIM + NROWS);
}

// Round 7
// 223.434 us; speedup vs baseline: 2.0144x; 1.1938x over previous
//
#include <hip/hip_runtime.h>
#include <math.h>
#include <float.h>

#define NROWS 16384
#define KCODES 8192
#define DIM 256

// ws layout (4B units)
#define WS_CKEY 0                                  // 16384*32 u64 = 4 MB
#define WS_ZZ   (NROWS * 64)
#define WS_EE   (WS_ZZ + NROWS)
#define WS_LOSS (WS_EE + KCODES)
#define WS_ZB   (WS_LOSS + 64)                     // z bf16
#define WS_EB   (WS_ZB + NROWS * DIM / 2)          // emb bf16

typedef __attribute__((ext_vector_type(8))) short bf16x8;
typedef __attribute__((ext_vector_type(4))) float f32x4;
typedef unsigned long long u64;

__device__ __forceinline__ unsigned cvt2(float lo, float hi) {
  unsigned r;
  asm("v_cvt_pk_bf16_f32 %0, %1, %2" : "=v"(r) : "v"(lo), "v"(hi));
  return r;
}
__device__ __forceinline__ void gl_lds16(const void* gsrc, void* lds) {
  __builtin_amdgcn_global_load_lds(
      (const __attribute__((address_space(1))) unsigned int*)gsrc,
      (__attribute__((address_space(3))) unsigned int*)lds, 16, 0, 0);
}
__device__ __forceinline__ unsigned umn(unsigned a, unsigned b) { return a < b ? a : b; }
__device__ __forceinline__ unsigned umx(unsigned a, unsigned b) { return a > b ? a : b; }
__device__ __forceinline__ void ce32(unsigned& a, unsigned& b) {
  unsigned lo = umn(a, b); b = umx(a, b); a = lo;
}
__device__ __forceinline__ void mrg4(unsigned m[4], const unsigned o[4]) {
  m[0] = umn(m[0], o[3]); m[1] = umn(m[1], o[2]);
  m[2] = umn(m[2], o[1]); m[3] = umn(m[3], o[0]);
  ce32(m[0], m[2]); ce32(m[1], m[3]); ce32(m[0], m[1]); ce32(m[2], m[3]);
}
__device__ __forceinline__ void sort4(unsigned& a, unsigned& b, unsigned& c, unsigned& d) {
  ce32(a, b); ce32(c, d); ce32(a, c); ce32(b, d); ce32(b, c);
}

// ---- exact numpy scalar-pairwise sum of squares over 256 contiguous f32 ----
__device__ __forceinline__ float np_sumsq256(const float* __restrict__ p) {
#pragma clang fp contract(off)
  float s0 = 0.f, s1 = 0.f;
  for (int h = 0; h < 2; ++h) {
    const float* x = p + h * 128;
    float r0, r1, r2, r3, r4, r5, r6, r7;
    {
      float4 a = *reinterpret_cast<const float4*>(x);
      float4 b = *reinterpret_cast<const float4*>(x + 4);
      r0 = a.x * a.x; r1 = a.y * a.y; r2 = a.z * a.z; r3 = a.w * a.w;
      r4 = b.x * b.x; r5 = b.y * b.y; r6 = b.z * b.z; r7 = b.w * b.w;
    }
    for (int g = 1; g < 16; ++g) {
      float4 a = *reinterpret_cast<const float4*>(x + g * 8);
      float4 b = *reinterpret_cast<const float4*>(x + g * 8 + 4);
      float p0 = a.x * a.x, p1 = a.y * a.y, p2 = a.z * a.z, p3 = a.w * a.w;
      float p4 = b.x * b.x, p5 = b.y * b.y, p6 = b.z * b.z, p7 = b.w * b.w;
      r0 += p0; r1 += p1; r2 += p2; r3 += p3;
      r4 += p4; r5 += p5; r6 += p6; r7 += p7;
    }
    float t = ((r0 + r1) + (r2 + r3)) + ((r4 + r5) + (r6 + r7));
    if (h == 0) s0 = t; else s1 = t;
  }
  return s0 + s1;
}

__global__ __launch_bounds__(256) void vq_prep_zz(const float* __restrict__ z,
                                                  float* __restrict__ zz,
                                                  float* __restrict__ lossAcc) {
  const int row = blockIdx.x * 256 + threadIdx.x;
  if (row == 0) *lossAcc = 0.0f;
  zz[row] = np_sumsq256(z + row * DIM);
}

__global__ __launch_bounds__(256) void vq_prep_ee(const float* __restrict__ emb,
                                                  float* __restrict__ ee) {
  const int c = blockIdx.x * 256 + threadIdx.x;
  ee[c] = np_sumsq256(emb + c * DIM);
}

// ---- f32 -> bf16 conversion of z and emb ----
#define CVT_ZBLK (NROWS * DIM / 8 / 256)    // 2048
#define CVT_EBLK (KCODES * DIM / 8 / 256)   // 1024
__global__ __launch_bounds__(256) void vq_cvt(const float* __restrict__ z,
                                              const float* __restrict__ emb,
                                              uint4* __restrict__ zb,
                                              uint4* __restrict__ eb) {
  const int bid = blockIdx.x;
  const float* s;
  uint4* d;
  int i;
  if (bid < CVT_ZBLK) { s = z; d = zb; i = bid * 256 + threadIdx.x; }
  else { s = emb; d = eb; i = (bid - CVT_ZBLK) * 256 + threadIdx.x; }
  const float4 a = *reinterpret_cast<const float4*>(s + i * 8);
  const float4 b = *reinterpret_cast<const float4*>(s + i * 8 + 4);
  d[i] = make_uint4(cvt2(a.x, a.y), cvt2(a.z, a.w), cvt2(b.x, b.y), cvt2(b.z, b.w));
}

// ---------------- stage A: bf16 MFMA ranking -> sorted top-4 u64 keys per 1024-code range ----------------
__global__ __launch_bounds__(256, 2) void vq_stageA(const unsigned* __restrict__ zb,
                                                    const unsigned* __restrict__ eb,
                                                    u64* __restrict__ candKey) {
  __shared__ short es[256 * 64];                 // 32 KB (merge buf aliased)
  __shared__ short zs[128 * 64];                 // 16 KB

  const int tid = threadIdx.x;
  const int wave = tid >> 6, lane = tid & 63;
  const int wr = wave >> 1, wc = wave & 1;
  const int g = lane >> 4, r16 = lane & 15;
  const int rowBase = blockIdx.x * 128;
  const int crange = blockIdx.y;
  const int swz = (r16 & 7) << 4;

  const int l8 = lane >> 3, l7 = lane & 7;
  const int swzoff = ((l7 ^ l8) << 4);
  const char* ebB = reinterpret_cast<const char*>(eb);
  const char* zbB = reinterpret_cast<const char*>(zb);
  const char* zsrc = zbB + (size_t)(rowBase + wave * 32 + l8) * 512 + swzoff;
  char* esDst = reinterpret_cast<char*>(es) + wave * 8 * 1024;
  char* zsDst = reinterpret_cast<char*>(zs) + wave * 4 * 1024;

  unsigned run[4][4];
  #pragma unroll
  for (int bj = 0; bj < 4; ++bj)
    #pragma unroll
    for (int q = 0; q < 4; ++q) run[bj][q] = 0xFFFFFFFFu;

  for (int cc = 0; cc < 4; ++cc) {
    const char* esrc = ebB + (size_t)(crange * 1024 + cc * 256 + wave * 64 + l8) * 512 + swzoff;
    f32x4 acc[8][4];
    #pragma unroll
    for (int ai = 0; ai < 8; ++ai)
      #pragma unroll
      for (int bj = 0; bj < 4; ++bj) acc[ai][bj] = (f32x4){0.f, 0.f, 0.f, 0.f};

    for (int kc = 0; kc < 4; ++kc) {
      #pragma unroll
      for (int i = 0; i < 8; ++i)
        gl_lds16(esrc + i * 4096 + kc * 128, esDst + i * 1024);
      #pragma unroll
      for (int i = 0; i < 4; ++i)
        gl_lds16(zsrc + i * 4096 + kc * 128, zsDst + i * 1024);
      __syncthreads();

      #pragma unroll
      for (int ks2 = 0; ks2 < 2; ++ks2) {
        const int kb = ks2 * 64 + g * 16;
        bf16x8 A[8], B[4];
        #pragma unroll
        for (int ai = 0; ai < 8; ++ai) {
          const int cl = wc * 128 + ai * 16 + r16;
          A[ai] = *reinterpret_cast<const bf16x8*>(
              reinterpret_cast<const char*>(es) + ((cl * 128 + kb) ^ swz));
        }
        #pragma unroll
        for (int bj = 0; bj < 4; ++bj) {
          const int rl = wr * 64 + bj * 16 + r16;
          B[bj] = *reinterpret_cast<const bf16x8*>(
              reinterpret_cast<const char*>(zs) + ((rl * 128 + kb) ^ swz));
        }
        #pragma unroll
        for (int ai = 0; ai < 8; ++ai)
          #pragma unroll
          for (int bj = 0; bj < 4; ++bj)
            acc[ai][bj] = __builtin_amdgcn_mfma_f32_16x16x32_bf16(A[ai], B[bj], acc[ai][bj], 0, 0, 0);
      }
      __syncthreads();
    }

    #pragma unroll
    for (int bj = 0; bj < 4; ++bj) {
      unsigned q4[8][4];
      #pragma unroll
      for (int ai = 0; ai < 8; ++ai) {
        const unsigned base9 = (cc << 7) | (ai << 4) | (g << 2);
        unsigned k0 = (__float_as_uint(1.5f - acc[ai][bj][0]) << 9) | base9;
        unsigned k1 = (__float_as_uint(1.5f - acc[ai][bj][1]) << 9) | (base9 + 1);
        unsigned k2 = (__float_as_uint(1.5f - acc[ai][bj][2]) << 9) | (base9 + 2);
        unsigned k3 = (__float_as_uint(1.5f - acc[ai][bj][3]) << 9) | (base9 + 3);
        sort4(k0, k1, k2, k3);
        q4[ai][0] = k0; q4[ai][1] = k1; q4[ai][2] = k2; q4[ai][3] = k3;
      }
      mrg4(q4[0], q4[1]); mrg4(q4[2], q4[3]); mrg4(q4[4], q4[5]); mrg4(q4[6], q4[7]);
      mrg4(q4[0], q4[2]); mrg4(q4[4], q4[6]);
      mrg4(q4[0], q4[4]);
      mrg4(run[bj], q4[0]);
    }
  }

  #pragma unroll
  for (int bj = 0; bj < 4; ++bj) {
    #pragma unroll
    for (int m = 16; m < 64; m <<= 1) {
      unsigned o[4];
      #pragma unroll
      for (int q = 0; q < 4; ++q) o[q] = __shfl_xor(run[bj][q], m, 64);
      mrg4(run[bj], o);
    }
  }
  u64 (*mrgp)[2][4] = reinterpret_cast<u64(*)[2][4]>(es);
  if (lane < 16) {
    #pragma unroll
    for (int bj = 0; bj < 4; ++bj) {
      const int rl = wr * 64 + bj * 16 + r16;
      #pragma unroll
      for (int q = 0; q < 4; ++q) {
        const unsigned k = run[bj][q];
        const unsigned cid = k & 511u;
        const unsigned cir = ((cid >> 7) << 8) | (wc << 7) | (cid & 127u);
        mrgp[rl][wc][q] = (((u64)(k >> 9)) << 10) | cir;
      }
    }
  }
  __syncthreads();
  if (tid < 128) {
    u64 a0 = mrgp[tid][0][0], a1 = mrgp[tid][0][1], a2 = mrgp[tid][0][2], a3 = mrgp[tid][0][3];
    u64 b0 = mrgp[tid][1][0], b1 = mrgp[tid][1][1], b2 = mrgp[tid][1][2], b3 = mrgp[tid][1][3];
    a0 = a0 < b3 ? a0 : b3; a1 = a1 < b2 ? a1 : b2;
    a2 = a2 < b1 ? a2 : b1; a3 = a3 < b0 ? a3 : b0;
    u64 t;
    if (a2 < a0) { t = a0; a0 = a2; a2 = t; }
    if (a3 < a1) { t = a1; a1 = a3; a3 = t; }
    if (a1 < a0) { t = a0; a0 = a1; a1 = t; }
    if (a3 < a2) { t = a2; a2 = a3; a3 = t; }
    const unsigned base = crange * 1024;
    u64* dst = candKey + (size_t)(rowBase + tid) * 32 + crange * 4;
    dst[0] = ((a0 >> 10) << 13) | (base + (unsigned)(a0 & 1023u));
    dst[1] = ((a1 >> 10) << 13) | (base + (unsigned)(a1 & 1023u));
    dst[2] = ((a2 >> 10) << 13) | (base + (unsigned)(a2 & 1023u));
    dst[3] = ((a3 >> 10) << 13) | (base + (unsigned)(a3 & 1023u));
  }
}

// ---------------- stage B: global top-8 select (bitonic-32 on u64 keys) + exact np-f32 re-score ----------------
// Block: 32 z-rows. Phase 1: per row, sort its 32 range-keys, keep 8 best.
// Phase 2: 32 rows x 8 slots = 256 chains, emb staged via LDS (4 k-chunks).
__global__ __launch_bounds__(256) void vq_stageB(const float* __restrict__ z,
                                                 const float* __restrict__ emb,
                                                 const float* __restrict__ zz,
                                                 const float* __restrict__ ee,
                                                 const u64* __restrict__ candKey,
                                                 float* __restrict__ outq,
                                                 float* __restrict__ outi,
                                                 float* __restrict__ lossAcc) {
#pragma clang fp contract(off)
  __shared__ float els[256 * 65];   // 66.56 KB
  __shared__ float zls[32 * 68];    // 8.7 KB
  __shared__ int cands8[32][8];
  __shared__ float lred[4];

  const int tid = threadIdx.x;
  const int wave = tid >> 6, lane = tid & 63;
  const int rowBase = blockIdx.x * 32;

  // ---- phase 1: top-8 of 32 keys per row (wave handles 2 rows per iteration) ----
  const int h = lane >> 5, l32 = lane & 31;
  #pragma unroll
  for (int it = 0; it < 4; ++it) {
    const int p = wave * 4 + it;                  // row pair 0..15
    const int r = p * 2 + h;                      // row in block 0..31
    u64 key = candKey[(size_t)(rowBase + r) * 32 + l32];
    #pragma unroll
    for (int k = 2; k <= 32; k <<= 1) {
      #pragma unroll
      for (int j = k >> 1; j > 0; j >>= 1) {
        const u64 partner = __shfl_xor(key, j, 64);
        const bool up = (l32 & k) == 0;
        const bool lower = (l32 & j) == 0;
        const u64 mnv = key < partner ? key : partner;
        const u64 mxv = key < partner ? partner : key;
        key = (lower == up) ? mnv : mxv;
      }
    }
    if (l32 < 8) cands8[r][l32] = (int)(key & 8191u);
  }
  __syncthreads();

  // ---- phase 2: exact chains ----
  const int grp = tid >> 3;              // row in block 0..31
  const int slot = tid & 7;              // candidate 0..7
  const int row = rowBase + grp;
  const int ci = cands8[grp][slot];

  float acc = 0.0f;
  #pragma unroll 1
  for (int chunk = 0; chunk < 4; ++chunk) {
    #pragma unroll
    for (int it = 0; it < 8; ++it) {
      const int f = it * 256 + tid;
      const int zr = f >> 6, zk = f & 63;
      zls[zr * 68 + zk] = z[(rowBase + zr) * DIM + chunk * 64 + zk];
    }
    #pragma unroll 8
    for (int it = 0; it < 64; ++it) {
      const int slice = it * 4 + wave;
      const int sci = (&cands8[0][0])[slice];
      els[slice * 65 + lane] = emb[sci * DIM + chunk * 64 + lane];
    }
    __syncthreads();
    const float* myE = els + tid * 65;
    const float* myZ = zls + grp * 68;
    #pragma unroll 16
    for (int k = 0; k < 64; ++k)
      acc = fmaf(myZ[k], myE[k], acc);
    __syncthreads();
  }

  // literal np sequence: d = fl(fl(zz + ee) - fl(2*mm)); lexmin (s-bits, idx)
  const float t = zz[row] + ee[ci];
  const float m2 = 2.0f * acc;
  const float s = t - m2;

  u64 pk = (((u64)__float_as_uint(s)) << 32) | (unsigned)ci;
  #pragma unroll
  for (int m = 1; m < 8; m <<= 1) {
    const u64 o = __shfl_xor(pk, m, 64);
    pk = (o < pk) ? o : pk;
  }
  const int bi = (int)(pk & 0xffffffffu);

  const float4* eb4 = reinterpret_cast<const float4*>(emb + bi * DIM);
  const float4* zb4 = reinterpret_cast<const float4*>(z + row * DIM);
  float l = 0.0f;
  #pragma unroll
  for (int q = 0; q < 8; ++q) {
    const float4 e4 = eb4[slot * 8 + q];
    const float4 z4 = zb4[slot * 8 + q];
    float4 o4;
    const float dx = e4.x - z4.x, dy = e4.y - z4.y, dz = e4.z - z4.z, dw = e4.w - z4.w;
    o4.x = z4.x + dx; o4.y = z4.y + dy; o4.z = z4.z + dz; o4.w = z4.w + dw;
    *reinterpret_cast<float4*>(outq + row * DIM + slot * 32 + q * 4) = o4;
    l += dx * dx; l += dy * dy; l += dz * dz; l += dw * dw;
  }
  if (slot == 0) outi[row] = (float)bi;

  #pragma unroll
  for (int m = 1; m < 64; m <<= 1) l += __shfl_xor(l, m, 64);
  if (lane == 0) lred[wave] = l;
  __syncthreads();
  if (tid == 0)
    atomicAdd(lossAcc, lred[0] + lred[1] + lred[2] + lred[3]);
}

__global__ void vq_fin(const float* __restrict__ lossAcc, float* __restrict__ outLoss) {
  *outLoss = 1.25f * (*lossAcc) * (1.0f / 4194304.0f);
}

extern "C" void kernel_launch(void* const* d_in, const int* in_sizes, int n_in,
                              void* d_out, int out_size, void* d_ws, size_t ws_size,
                              hipStream_t stream) {
  const float* z = (const float*)d_in[0];
  const float* emb = (const float*)d_in[1];
  float* out = (float*)d_out;
  float* wsf = (float*)d_ws;
  u64* candKey = (u64*)(wsf + WS_CKEY);
  float* zz = wsf + WS_ZZ;
  float* ee = wsf + WS_EE;
  float* lossAcc = wsf + WS_LOSS;
  uint4* zb = (uint4*)(wsf + WS_ZB);
  uint4* eb = (uint4*)(wsf + WS_EB);

  vq_prep_zz<<<NROWS / 256, 256, 0, stream>>>(z, zz, lossAcc);
  vq_prep_ee<<<KCODES / 256, 256, 0, stream>>>(emb, ee);
  vq_cvt<<<CVT_ZBLK + CVT_EBLK, 256, 0, stream>>>(z, emb, zb, eb);
  vq_stageA<<<dim3(NROWS / 128, 8), 256, 0, stream>>>((const unsigned*)zb, (const unsigned*)eb, candKey);
  vq_stageB<<<NROWS / 32, 256, 0, stream>>>(z, emb, zz, ee, candKey,
                                            out, out + NROWS * DIM, lossAcc);
  vq_fin<<<1, 1, 0, stream>>>(lossAcc, out + NROWS * DIM + NROWS);
}

// Round 8
// 195.872 us; speedup vs baseline: 2.2979x; 1.1407x over previous
//
#include <hip/hip_runtime.h>
#include <math.h>
#include <float.h>

#define NROWS 16384
#define KCODES 8192
#define DIM 256

// ws layout (4B units)
#define WS_CKEY 0                                  // 16384*32 u64 = 4 MB
#define WS_ZZ   (NROWS * 64)
#define WS_EE   (WS_ZZ + NROWS)
#define WS_LOSS (WS_EE + KCODES)
#define WS_ZB   (WS_LOSS + 64)                     // z bf16
#define WS_EB   (WS_ZB + NROWS * DIM / 2)          // emb bf16

typedef __attribute__((ext_vector_type(8))) short bf16x8;
typedef __attribute__((ext_vector_type(4))) float f32x4;
typedef unsigned long long u64;

__device__ __forceinline__ unsigned cvt2(float lo, float hi) {
  unsigned r;
  asm("v_cvt_pk_bf16_f32 %0, %1, %2" : "=v"(r) : "v"(lo), "v"(hi));
  return r;
}
__device__ __forceinline__ void gl_lds16(const void* gsrc, void* lds) {
  __builtin_amdgcn_global_load_lds(
      (const __attribute__((address_space(1))) unsigned int*)gsrc,
      (__attribute__((address_space(3))) unsigned int*)lds, 16, 0, 0);
}
__device__ __forceinline__ unsigned umn(unsigned a, unsigned b) { return a < b ? a : b; }
__device__ __forceinline__ unsigned umx(unsigned a, unsigned b) { return a > b ? a : b; }
__device__ __forceinline__ void ce32(unsigned& a, unsigned& b) {
  unsigned lo = umn(a, b); b = umx(a, b); a = lo;
}
__device__ __forceinline__ void mrg4(unsigned m[4], const unsigned o[4]) {
  m[0] = umn(m[0], o[3]); m[1] = umn(m[1], o[2]);
  m[2] = umn(m[2], o[1]); m[3] = umn(m[3], o[0]);
  ce32(m[0], m[2]); ce32(m[1], m[3]); ce32(m[0], m[1]); ce32(m[2], m[3]);
}
__device__ __forceinline__ void sort4(unsigned& a, unsigned& b, unsigned& c, unsigned& d) {
  ce32(a, b); ce32(c, d); ce32(a, c); ce32(b, d); ce32(b, c);
}

// ---------------- fused prep: bf16 convert + exact np sumsq (zz, ee) + loss zero ----------------
// grid: 1024 z-blocks + 512 emb-blocks; block = 16 rows.
// sumsq: 16 threads/row = (half h, accumulator j); scalar v*v then += (contract off) in np's
// exact order; tree-combined via shfl_xor 1,2,4 (j-tree) then 8 (s0+s1).
__global__ __launch_bounds__(256) void vq_prep(const float* __restrict__ z,
                                               const float* __restrict__ emb,
                                               float* __restrict__ zz,
                                               float* __restrict__ ee,
                                               uint2* __restrict__ zb2,
                                               uint2* __restrict__ eb2,
                                               float* __restrict__ lossAcc) {
#pragma clang fp contract(off)
  const int tid = threadIdx.x;
  const int bid = blockIdx.x;
  if (bid == 0 && tid == 0) *lossAcc = 0.0f;
  const bool isZ = bid < (NROWS / 16);
  const int row0 = (isZ ? bid : bid - NROWS / 16) * 16;
  const float* src = isZ ? z : emb;
  uint2* dst = isZ ? zb2 : eb2;
  float* sums = isZ ? zz : ee;

  // part A: convert 16 rows (1024 float4) to bf16
  const float4* src4 = reinterpret_cast<const float4*>(src) + row0 * 64;
  uint2* d2 = dst + row0 * 64;
  #pragma unroll
  for (int it = 0; it < 4; ++it) {
    const int f4 = it * 256 + tid;
    const float4 a = src4[f4];
    d2[f4] = make_uint2(cvt2(a.x, a.y), cvt2(a.z, a.w));
  }

  // part B: exact np sumsq chains
  const int row = row0 + (tid >> 4);
  const int h = (tid >> 3) & 1;
  const int j = tid & 7;
  const float* x = src + row * DIM + h * 128 + j;
  float v = x[0];
  float r = v * v;
  #pragma unroll
  for (int g = 1; g < 16; ++g) {
    v = x[g * 8];
    const float p = v * v;
    r = r + p;
  }
  r = r + __shfl_xor(r, 1, 64);
  r = r + __shfl_xor(r, 2, 64);
  r = r + __shfl_xor(r, 4, 64);
  r = r + __shfl_xor(r, 8, 64);
  if ((tid & 15) == 0) sums[row] = r;
}

// ---------------- stage A: bf16 MFMA ranking -> sorted top-4 u64 keys per 1024-code range ----------------
__global__ __launch_bounds__(256, 2) void vq_stageA(const unsigned* __restrict__ zb,
                                                    const unsigned* __restrict__ eb,
                                                    u64* __restrict__ candKey) {
  __shared__ short es[256 * 64];                 // 32 KB (merge buf aliased)
  __shared__ short zs[128 * 64];                 // 16 KB

  const int tid = threadIdx.x;
  const int wave = tid >> 6, lane = tid & 63;
  const int wr = wave >> 1, wc = wave & 1;
  const int g = lane >> 4, r16 = lane & 15;
  const int rowBase = blockIdx.x * 128;
  const int crange = blockIdx.y;
  const int swz = (r16 & 7) << 4;

  const int l8 = lane >> 3, l7 = lane & 7;
  const int swzoff = ((l7 ^ l8) << 4);
  const char* ebB = reinterpret_cast<const char*>(eb);
  const char* zbB = reinterpret_cast<const char*>(zb);
  const char* zsrc = zbB + (size_t)(rowBase + wave * 32 + l8) * 512 + swzoff;
  char* esDst = reinterpret_cast<char*>(es) + wave * 8 * 1024;
  char* zsDst = reinterpret_cast<char*>(zs) + wave * 4 * 1024;

  unsigned run[4][4];
  #pragma unroll
  for (int bj = 0; bj < 4; ++bj)
    #pragma unroll
    for (int q = 0; q < 4; ++q) run[bj][q] = 0xFFFFFFFFu;

  for (int cc = 0; cc < 4; ++cc) {
    const char* esrc = ebB + (size_t)(crange * 1024 + cc * 256 + wave * 64 + l8) * 512 + swzoff;
    f32x4 acc[8][4];
    #pragma unroll
    for (int ai = 0; ai < 8; ++ai)
      #pragma unroll
      for (int bj = 0; bj < 4; ++bj) acc[ai][bj] = (f32x4){0.f, 0.f, 0.f, 0.f};

    for (int kc = 0; kc < 4; ++kc) {
      #pragma unroll
      for (int i = 0; i < 8; ++i)
        gl_lds16(esrc + i * 4096 + kc * 128, esDst + i * 1024);
      #pragma unroll
      for (int i = 0; i < 4; ++i)
        gl_lds16(zsrc + i * 4096 + kc * 128, zsDst + i * 1024);
      __syncthreads();

      #pragma unroll
      for (int ks2 = 0; ks2 < 2; ++ks2) {
        const int kb = ks2 * 64 + g * 16;
        bf16x8 A[8], B[4];
        #pragma unroll
        for (int ai = 0; ai < 8; ++ai) {
          const int cl = wc * 128 + ai * 16 + r16;
          A[ai] = *reinterpret_cast<const bf16x8*>(
              reinterpret_cast<const char*>(es) + ((cl * 128 + kb) ^ swz));
        }
        #pragma unroll
        for (int bj = 0; bj < 4; ++bj) {
          const int rl = wr * 64 + bj * 16 + r16;
          B[bj] = *reinterpret_cast<const bf16x8*>(
              reinterpret_cast<const char*>(zs) + ((rl * 128 + kb) ^ swz));
        }
        #pragma unroll
        for (int ai = 0; ai < 8; ++ai)
          #pragma unroll
          for (int bj = 0; bj < 4; ++bj)
            acc[ai][bj] = __builtin_amdgcn_mfma_f32_16x16x32_bf16(A[ai], B[bj], acc[ai][bj], 0, 0, 0);
      }
      __syncthreads();
    }

    #pragma unroll
    for (int bj = 0; bj < 4; ++bj) {
      unsigned q4[8][4];
      #pragma unroll
      for (int ai = 0; ai < 8; ++ai) {
        const unsigned base9 = (cc << 7) | (ai << 4) | (g << 2);
        unsigned k0 = (__float_as_uint(1.5f - acc[ai][bj][0]) << 9) | base9;
        unsigned k1 = (__float_as_uint(1.5f - acc[ai][bj][1]) << 9) | (base9 + 1);
        unsigned k2 = (__float_as_uint(1.5f - acc[ai][bj][2]) << 9) | (base9 + 2);
        unsigned k3 = (__float_as_uint(1.5f - acc[ai][bj][3]) << 9) | (base9 + 3);
        sort4(k0, k1, k2, k3);
        q4[ai][0] = k0; q4[ai][1] = k1; q4[ai][2] = k2; q4[ai][3] = k3;
      }
      mrg4(q4[0], q4[1]); mrg4(q4[2], q4[3]); mrg4(q4[4], q4[5]); mrg4(q4[6], q4[7]);
      mrg4(q4[0], q4[2]); mrg4(q4[4], q4[6]);
      mrg4(q4[0], q4[4]);
      mrg4(run[bj], q4[0]);
    }
  }

  #pragma unroll
  for (int bj = 0; bj < 4; ++bj) {
    #pragma unroll
    for (int m = 16; m < 64; m <<= 1) {
      unsigned o[4];
      #pragma unroll
      for (int q = 0; q < 4; ++q) o[q] = __shfl_xor(run[bj][q], m, 64);
      mrg4(run[bj], o);
    }
  }
  u64 (*mrgp)[2][4] = reinterpret_cast<u64(*)[2][4]>(es);
  if (lane < 16) {
    #pragma unroll
    for (int bj = 0; bj < 4; ++bj) {
      const int rl = wr * 64 + bj * 16 + r16;
      #pragma unroll
      for (int q = 0; q < 4; ++q) {
        const unsigned k = run[bj][q];
        const unsigned cid = k & 511u;
        const unsigned cir = ((cid >> 7) << 8) | (wc << 7) | (cid & 127u);
        mrgp[rl][wc][q] = (((u64)(k >> 9)) << 10) | cir;
      }
    }
  }
  __syncthreads();
  if (tid < 128) {
    u64 a0 = mrgp[tid][0][0], a1 = mrgp[tid][0][1], a2 = mrgp[tid][0][2], a3 = mrgp[tid][0][3];
    u64 b0 = mrgp[tid][1][0], b1 = mrgp[tid][1][1], b2 = mrgp[tid][1][2], b3 = mrgp[tid][1][3];
    a0 = a0 < b3 ? a0 : b3; a1 = a1 < b2 ? a1 : b2;
    a2 = a2 < b1 ? a2 : b1; a3 = a3 < b0 ? a3 : b0;
    u64 t;
    if (a2 < a0) { t = a0; a0 = a2; a2 = t; }
    if (a3 < a1) { t = a1; a1 = a3; a3 = t; }
    if (a1 < a0) { t = a0; a0 = a1; a1 = t; }
    if (a3 < a2) { t = a2; a2 = a3; a3 = t; }
    const unsigned base = crange * 1024;
    u64* dst = candKey + (size_t)(rowBase + tid) * 32 + crange * 4;
    dst[0] = ((a0 >> 10) << 13) | (base + (unsigned)(a0 & 1023u));
    dst[1] = ((a1 >> 10) << 13) | (base + (unsigned)(a1 & 1023u));
    dst[2] = ((a2 >> 10) << 13) | (base + (unsigned)(a2 & 1023u));
    dst[3] = ((a3 >> 10) << 13) | (base + (unsigned)(a3 & 1023u));
  }
}

// ---------------- stage B: global top-8 select + exact np-f32 re-score (vectorized staging) ----------------
__global__ __launch_bounds__(256) void vq_stageB(const float* __restrict__ z,
                                                 const float* __restrict__ emb,
                                                 const float* __restrict__ zz,
                                                 const float* __restrict__ ee,
                                                 const u64* __restrict__ candKey,
                                                 float* __restrict__ outq,
                                                 float* __restrict__ outi,
                                                 float* __restrict__ lossAcc) {
#pragma clang fp contract(off)
  __shared__ float els[256 * 65];   // 66.56 KB, stride 65 (chain reads 2-way free)
  __shared__ float zls[32 * 68];    // stride 68 (b128-aligned, conflict-free)
  __shared__ int cands8[32][8];
  __shared__ float lred[4];

  const int tid = threadIdx.x;
  const int wave = tid >> 6, lane = tid & 63;
  const int rowBase = blockIdx.x * 32;

  // ---- phase 1: top-8 of 32 keys per row (bitonic-32 per 32-lane half) ----
  const int h = lane >> 5, l32 = lane & 31;
  #pragma unroll
  for (int it = 0; it < 4; ++it) {
    const int p = wave * 4 + it;
    const int r = p * 2 + h;
    u64 key = candKey[(size_t)(rowBase + r) * 32 + l32];
    #pragma unroll
    for (int k = 2; k <= 32; k <<= 1) {
      #pragma unroll
      for (int j = k >> 1; j > 0; j >>= 1) {
        const u64 partner = __shfl_xor(key, j, 64);
        const bool up = (l32 & k) == 0;
        const bool lower = (l32 & j) == 0;
        const u64 mnv = key < partner ? key : partner;
        const u64 mxv = key < partner ? partner : key;
        key = (lower == up) ? mnv : mxv;
      }
    }
    if (l32 < 8) cands8[r][l32] = (int)(key & 8191u);
  }
  __syncthreads();

  // ---- phase 2: exact chains (32 rows x 8 slots) ----
  const int grp = tid >> 3;
  const int slot = tid & 7;
  const int row = rowBase + grp;
  const int ci = cands8[grp][slot];
  const int q16 = tid >> 4, part = tid & 15;
  const float4* emb4 = reinterpret_cast<const float4*>(emb);
  const float4* z4base = reinterpret_cast<const float4*>(z + rowBase * DIM);
  const int* cflat = &cands8[0][0];

  float acc = 0.0f;
  #pragma unroll 1
  for (int chunk = 0; chunk < 4; ++chunk) {
    // z staging: 512 float4 in 2 insts
    #pragma unroll
    for (int it = 0; it < 2; ++it) {
      const int f4 = it * 256 + tid;
      const int zr = f4 >> 4, zp = f4 & 15;
      const float4 a = z4base[zr * 64 + chunk * 16 + zp];
      *reinterpret_cast<float4*>(&zls[zr * 68 + zp * 4]) = a;
    }
    // emb staging: 256 slices x 16 float4, 16 insts
    #pragma unroll
    for (int it = 0; it < 16; ++it) {
      const int slice = it * 16 + q16;
      const int sci = cflat[slice];
      const float4 a = emb4[sci * 64 + chunk * 16 + part];
      float* d = &els[slice * 65 + part * 4];
      d[0] = a.x; d[1] = a.y; d[2] = a.z; d[3] = a.w;
    }
    __syncthreads();
    const float* myE = els + tid * 65;
    const float* myZ = zls + grp * 68;
    #pragma unroll
    for (int k4 = 0; k4 < 64; k4 += 4) {
      const float4 zv = *reinterpret_cast<const float4*>(myZ + k4);
      acc = fmaf(zv.x, myE[k4 + 0], acc);
      acc = fmaf(zv.y, myE[k4 + 1], acc);
      acc = fmaf(zv.z, myE[k4 + 2], acc);
      acc = fmaf(zv.w, myE[k4 + 3], acc);
    }
    __syncthreads();
  }

  // literal np sequence: d = fl(fl(zz + ee) - fl(2*mm)); lexmin (s-bits, idx)
  const float t = zz[row] + ee[ci];
  const float m2 = 2.0f * acc;
  const float s = t - m2;

  u64 pk = (((u64)__float_as_uint(s)) << 32) | (unsigned)ci;
  #pragma unroll
  for (int m = 1; m < 8; m <<= 1) {
    const u64 o = __shfl_xor(pk, m, 64);
    pk = (o < pk) ? o : pk;
  }
  const int bi = (int)(pk & 0xffffffffu);

  const float4* eb4 = reinterpret_cast<const float4*>(emb + bi * DIM);
  const float4* zb4 = reinterpret_cast<const float4*>(z + row * DIM);
  float l = 0.0f;
  #pragma unroll
  for (int q = 0; q < 8; ++q) {
    const float4 e4 = eb4[slot * 8 + q];
    const float4 zv4 = zb4[slot * 8 + q];
    float4 o4;
    const float dx = e4.x - zv4.x, dy = e4.y - zv4.y, dz = e4.z - zv4.z, dw = e4.w - zv4.w;
    o4.x = zv4.x + dx; o4.y = zv4.y + dy; o4.z = zv4.z + dz; o4.w = zv4.w + dw;
    *reinterpret_cast<float4*>(outq + row * DIM + slot * 32 + q * 4) = o4;
    l += dx * dx; l += dy * dy; l += dz * dz; l += dw * dw;
  }
  if (slot == 0) outi[row] = (float)bi;

  #pragma unroll
  for (int m = 1; m < 64; m <<= 1) l += __shfl_xor(l, m, 64);
  if (lane == 0) lred[wave] = l;
  __syncthreads();
  if (tid == 0)
    atomicAdd(lossAcc, lred[0] + lred[1] + lred[2] + lred[3]);
}

__global__ void vq_fin(const float* __restrict__ lossAcc, float* __restrict__ outLoss) {
  *outLoss = 1.25f * (*lossAcc) * (1.0f / 4194304.0f);
}

extern "C" void kernel_launch(void* const* d_in, const int* in_sizes, int n_in,
                              void* d_out, int out_size, void* d_ws, size_t ws_size,
                              hipStream_t stream) {
  const float* z = (const float*)d_in[0];
  const float* emb = (const float*)d_in[1];
  float* out = (float*)d_out;
  float* wsf = (float*)d_ws;
  u64* candKey = (u64*)(wsf + WS_CKEY);
  float* zz = wsf + WS_ZZ;
  float* ee = wsf + WS_EE;
  float* lossAcc = wsf + WS_LOSS;
  uint2* zb2 = (uint2*)(wsf + WS_ZB);
  uint2* eb2 = (uint2*)(wsf + WS_EB);

  vq_prep<<<NROWS / 16 + KCODES / 16, 256, 0, stream>>>(z, emb, zz, ee, zb2, eb2, lossAcc);
  vq_stageA<<<dim3(NROWS / 128, 8), 256, 0, stream>>>((const unsigned*)zb2, (const unsigned*)eb2, candKey);
  vq_stageB<<<NROWS / 32, 256, 0, stream>>>(z, emb, zz, ee, candKey,
                                            out, out + NROWS * DIM, lossAcc);
  vq_fin<<<1, 1, 0, stream>>>(lossAcc, out + NROWS * DIM + NROWS);
}